// Round 1
// baseline (160.883 us; speedup 1.0000x reference)
//
#include <hip/hip_runtime.h>

#define NN 17    // nodes / landmarks
#define D  512   // feature dim
#define H  8     // heads
#define C1 515   // D + 3 coords
#define M  256   // hidden

// K1: f[h,n,e] = relu(sum_d Xs[n,d] * FC[h,d,e])
// grid = H*NN blocks, block = 512 threads (one e per thread)
__global__ void k1_f(const float* __restrict__ Xs, const float* __restrict__ FC,
                     float* __restrict__ f) {
    const int h = blockIdx.x / NN, n = blockIdx.x % NN;
    const int t = threadIdx.x;
    __shared__ float xs[D];
    xs[t] = Xs[n * D + t];
    __syncthreads();
    const float* fc = FC + (size_t)h * D * D + t;
    float acc = 0.f;
#pragma unroll 8
    for (int d = 0; d < D; ++d) acc = fmaf(xs[d], fc[(size_t)d * D], acc);
    f[(h * NN + n) * D + t] = fmaxf(acc, 0.f);
}

// K2: hdn[h,n,m] = tanh(sum_c cat[h,n,c] * W1[h,c,m] + b1[h,m]); cat = [f_row, ROI_row]
// grid = H*NN blocks, block = 256 threads (one m per thread)
__global__ void k2_hdn(const float* __restrict__ f, const float* __restrict__ ROIs,
                       const float* __restrict__ W1, const float* __restrict__ b1,
                       float* __restrict__ hdn) {
    const int h = blockIdx.x / NN, n = blockIdx.x % NN;
    const int t = threadIdx.x;
    __shared__ float cat[C1];
    cat[t]       = f[(h * NN + n) * D + t];
    cat[t + 256] = f[(h * NN + n) * D + 256 + t];
    if (t < 3) cat[512 + t] = ROIs[n * 3 + t];
    __syncthreads();
    const float* w1 = W1 + (size_t)h * C1 * M + t;
    float acc = b1[h * M + t];
#pragma unroll 5
    for (int c = 0; c < C1; ++c) acc = fmaf(cat[c], w1[(size_t)c * M], acc);
    hdn[(h * NN + n) * M + t] = tanhf(acc);
}

// K3: att[h,n,k] = hdn[h,n,:] . W2[h,:,k] + b2[h,k]; then softmax over n per (h,k),
// stored transposed as att_sm[h,k,n]. grid = H blocks, block = 320 threads.
__global__ void k3_att(const float* __restrict__ hdn, const float* __restrict__ W2,
                       const float* __restrict__ b2, float* __restrict__ att) {
    const int h = blockIdx.x;
    const int t = threadIdx.x;
    __shared__ float sh[NN * M];    // hdn[h]
    __shared__ float sa[NN * NN];   // scores transposed [k][n]
    for (int i = t; i < NN * M; i += 320) sh[i] = hdn[h * NN * M + i];
    __syncthreads();
    if (t < NN * NN) {
        const int n = t / NN, k = t % NN;
        float acc = b2[h * NN + k];
        const float* w2 = W2 + (size_t)h * M * NN + k;
#pragma unroll 8
        for (int m = 0; m < M; ++m) acc = fmaf(sh[n * M + m], w2[m * NN], acc);
        sa[k * NN + n] = acc;
    }
    __syncthreads();
    if (t < NN) {
        const int k = t;
        float mx = -1e30f;
        for (int n = 0; n < NN; ++n) mx = fmaxf(mx, sa[k * NN + n]);
        float e[NN];
        float s = 0.f;
        for (int n = 0; n < NN; ++n) { e[n] = __expf(sa[k * NN + n] - mx); s += e[n]; }
        const float inv = 1.f / s;
        for (int n = 0; n < NN; ++n) att[(h * NN + k) * NN + n] = e[n] * inv;
    }
}

// K4: out[k,d] = relu(sum_h cw[h] * sum_n att_sm[h,k,n] * f[h,n,d] + cb) + Xs[k,d]
// plus ROI passthrough. grid = NN blocks, block = 512 threads (one d per thread).
__global__ void k4_out(const float* __restrict__ f, const float* __restrict__ att,
                       const float* __restrict__ conv_w, const float* __restrict__ conv_b,
                       const float* __restrict__ Xs, const float* __restrict__ ROIs,
                       float* __restrict__ out) {
    const int k = blockIdx.x, t = threadIdx.x;
    __shared__ float sa[H * NN];
    __shared__ float cw[H];
    if (t < H * NN) {
        const int h = t / NN, n = t % NN;
        sa[t] = att[(h * NN + k) * NN + n];
    }
    if (t < H) cw[t] = conv_w[t];
    __syncthreads();
    float acc = 0.f;
#pragma unroll
    for (int h = 0; h < H; ++h) {
        float wsum = 0.f;
#pragma unroll
        for (int n = 0; n < NN; ++n)
            wsum = fmaf(sa[h * NN + n], f[(h * NN + n) * D + t], wsum);
        acc = fmaf(cw[h], wsum, acc);
    }
    const float o = fmaxf(acc + conv_b[0], 0.f) + Xs[k * D + t];
    out[k * D + t] = o;
    if (k == 0 && t < NN * 3) out[NN * D + t] = ROIs[t];
}

extern "C" void kernel_launch(void* const* d_in, const int* in_sizes, int n_in,
                              void* d_out, int out_size, void* d_ws, size_t ws_size,
                              hipStream_t stream) {
    const float* Xs     = (const float*)d_in[0];
    const float* ROIs   = (const float*)d_in[1];
    // d_in[2] = adj, unused
    const float* FC     = (const float*)d_in[3];
    const float* W1     = (const float*)d_in[4];
    const float* b1     = (const float*)d_in[5];
    const float* W2     = (const float*)d_in[6];
    const float* b2     = (const float*)d_in[7];
    const float* conv_w = (const float*)d_in[8];
    const float* conv_b = (const float*)d_in[9];
    float* out = (float*)d_out;

    float* f   = (float*)d_ws;                 // H*NN*D  = 69632 floats
    float* hdn = f + H * NN * D;               // H*NN*M  = 34816 floats
    float* att = hdn + H * NN * M;             // H*NN*NN =  2312 floats

    k1_f  <<<H * NN, 512, 0, stream>>>(Xs, FC, f);
    k2_hdn<<<H * NN, 256, 0, stream>>>(f, ROIs, W1, b1, hdn);
    k3_att<<<H,      320, 0, stream>>>(hdn, W2, b2, att);
    k4_out<<<NN,     512, 0, stream>>>(f, att, conv_w, conv_b, Xs, ROIs, out);
}

// Round 3
// 120.958 us; speedup vs baseline: 1.3301x; 1.3301x over previous
//
#include <hip/hip_runtime.h>

#define NN 17    // nodes / landmarks
#define D  512   // feature dim
#define H  8     // heads
#define C1 515   // D + 3 coords
#define M  256   // hidden

// K1: f[h,n,e] = relu(sum_d Xs[n,d] * FC[h,d,e])
// grid = H*NN*4 blocks (e-tiles of 128), block = 128 threads.
// Thread t: tw=t&31 owns float4 of e; cg=t>>5 owns a 128-wide c-quarter.
__global__ void k1_f(const float* __restrict__ Xs, const float* __restrict__ FC,
                     float* __restrict__ f) {
    const int b = blockIdx.x;
    const int et = b & 3, hn = b >> 2;
    const int n = hn % NN, h = hn / NN;
    const int t = threadIdx.x, tw = t & 31, cg = t >> 5;
    __shared__ float xs[D];
    __shared__ float4 red[128];
    for (int i = t; i < D; i += 128) xs[i] = Xs[n * D + i];
    __syncthreads();
    const int e0 = et * 128 + tw * 4;
    const float4* fc = (const float4*)(FC + (size_t)h * D * D);
    float4 acc = {0.f, 0.f, 0.f, 0.f};
    const int c0 = cg * 128;
#pragma unroll 8
    for (int c = c0; c < c0 + 128; ++c) {
        const float4 w = fc[c * (D / 4) + (e0 >> 2)];
        const float x = xs[c];
        acc.x = fmaf(x, w.x, acc.x);
        acc.y = fmaf(x, w.y, acc.y);
        acc.z = fmaf(x, w.z, acc.z);
        acc.w = fmaf(x, w.w, acc.w);
    }
    red[t] = acc;
    __syncthreads();
    if (cg == 0) {
        const float4 a = red[tw], b2_ = red[32 + tw], c2 = red[64 + tw], d2 = red[96 + tw];
        float4 s;
        s.x = fmaxf(a.x + b2_.x + c2.x + d2.x, 0.f);
        s.y = fmaxf(a.y + b2_.y + c2.y + d2.y, 0.f);
        s.z = fmaxf(a.z + b2_.z + c2.z + d2.z, 0.f);
        s.w = fmaxf(a.w + b2_.w + c2.w + d2.w, 0.f);
        *(float4*)(f + (size_t)(h * NN + n) * D + e0) = s;
    }
}

// K2: hdn[h,n,m] = tanh(cat[h,n,:] . W1[h,:,m] + b1[h,m]); cat = [f_row, ROI_row]
// grid = H*NN*2 blocks (m-tiles of 128), block = 128 threads; c split 4-way.
__global__ void k2_hdn(const float* __restrict__ f, const float* __restrict__ ROIs,
                       const float* __restrict__ W1, const float* __restrict__ b1,
                       float* __restrict__ hdn) {
    const int b = blockIdx.x;
    const int mt = b & 1, hn = b >> 1;
    const int n = hn % NN, h = hn / NN;
    const int t = threadIdx.x, tw = t & 31, cg = t >> 5;
    __shared__ float cat[C1];
    __shared__ float4 red[128];
    for (int i = t; i < D; i += 128) cat[i] = f[(size_t)(h * NN + n) * D + i];
    if (t < 3) cat[D + t] = ROIs[n * 3 + t];
    __syncthreads();
    const int m0 = mt * 128 + tw * 4;
    const float* w1 = W1 + (size_t)h * C1 * M;
    const int cs = cg * 129;
    const int ce = (cs + 129 < C1) ? cs + 129 : C1;
    float4 acc = {0.f, 0.f, 0.f, 0.f};
#pragma unroll 4
    for (int c = cs; c < ce; ++c) {
        const float4 w = ((const float4*)(w1 + (size_t)c * M))[m0 >> 2];
        const float x = cat[c];
        acc.x = fmaf(x, w.x, acc.x);
        acc.y = fmaf(x, w.y, acc.y);
        acc.z = fmaf(x, w.z, acc.z);
        acc.w = fmaf(x, w.w, acc.w);
    }
    red[t] = acc;
    __syncthreads();
    if (cg == 0) {
        const float4 a = red[tw], b2_ = red[32 + tw], c2 = red[64 + tw], d2 = red[96 + tw];
        const float* bb = b1 + h * M + m0;
        float4 s;
        s.x = tanhf(a.x + b2_.x + c2.x + d2.x + bb[0]);
        s.y = tanhf(a.y + b2_.y + c2.y + d2.y + bb[1]);
        s.z = tanhf(a.z + b2_.z + c2.z + d2.z + bb[2]);
        s.w = tanhf(a.w + b2_.w + c2.w + d2.w + bb[3]);
        *(float4*)(hdn + (size_t)(h * NN + n) * M + m0) = s;
    }
}

// K3: att[h,n,k] = hdn[h,n,:] . W2[h,:,k] + b2[h,k]; softmax over n per (h,k),
// stored transposed att[h,k,n]. grid = H blocks, block = 320 threads.
__global__ void k3_att(const float* __restrict__ hdn, const float* __restrict__ W2,
                       const float* __restrict__ b2, float* __restrict__ att) {
    const int h = blockIdx.x;
    const int t = threadIdx.x;
    __shared__ float sh[NN * M];    // hdn[h]
    __shared__ float sw[M * NN];    // W2[h]
    __shared__ float sa[NN * NN];   // scores transposed [k][n]
    for (int i = t; i < NN * M; i += 320) sh[i] = hdn[h * NN * M + i];
    for (int i = t; i < M * NN; i += 320) sw[i] = W2[(size_t)h * M * NN + i];
    __syncthreads();
    if (t < NN * NN) {
        const int n = t / NN, k = t % NN;
        float acc = b2[h * NN + k];
#pragma unroll 8
        for (int m = 0; m < M; ++m) acc = fmaf(sh[n * M + m], sw[m * NN + k], acc);
        sa[k * NN + n] = acc;
    }
    __syncthreads();
    if (t < NN) {
        const int k = t;
        float mx = -1e30f;
        for (int n = 0; n < NN; ++n) mx = fmaxf(mx, sa[k * NN + n]);
        float e[NN];
        float s = 0.f;
        for (int n = 0; n < NN; ++n) { e[n] = __expf(sa[k * NN + n] - mx); s += e[n]; }
        const float inv = 1.f / s;
        for (int n = 0; n < NN; ++n) att[(h * NN + k) * NN + n] = e[n] * inv;
    }
}

// K4: out[k,d] = relu(sum_h cw[h] * sum_n att[h,k,n] * f[h,n,d] + cb) + Xs[k,d]
// grid = NN*4 blocks (d-tiles of 128), block = 128 threads.
__global__ void k4_out(const float* __restrict__ f, const float* __restrict__ att,
                       const float* __restrict__ conv_w, const float* __restrict__ conv_b,
                       const float* __restrict__ Xs, const float* __restrict__ ROIs,
                       float* __restrict__ out) {
    const int b = blockIdx.x;
    const int k = b >> 2, dt = b & 3;
    const int t = threadIdx.x;
    const int d = dt * 128 + t;
    __shared__ float sa[H * NN];
    __shared__ float cw[H];
    // NOTE: H*NN=136 > blockDim=128 — MUST be a strided loop (round-2 bug).
    for (int i = t; i < H * NN; i += 128) {
        const int h = i / NN, n = i % NN;
        sa[i] = att[(h * NN + k) * NN + n];
    }
    if (t < H) cw[t] = conv_w[t];
    __syncthreads();
    float acc = 0.f;
#pragma unroll
    for (int h = 0; h < H; ++h) {
        float wsum = 0.f;
#pragma unroll
        for (int n = 0; n < NN; ++n)
            wsum = fmaf(sa[h * NN + n], f[(size_t)(h * NN + n) * D + d], wsum);
        acc = fmaf(cw[h], wsum, acc);
    }
    out[k * D + d] = fmaxf(acc + conv_b[0], 0.f) + Xs[k * D + d];
    if (k == 0 && dt == 0 && t < NN * 3) out[NN * D + t] = ROIs[t];
}

extern "C" void kernel_launch(void* const* d_in, const int* in_sizes, int n_in,
                              void* d_out, int out_size, void* d_ws, size_t ws_size,
                              hipStream_t stream) {
    const float* Xs     = (const float*)d_in[0];
    const float* ROIs   = (const float*)d_in[1];
    // d_in[2] = adj, unused
    const float* FC     = (const float*)d_in[3];
    const float* W1     = (const float*)d_in[4];
    const float* b1     = (const float*)d_in[5];
    const float* W2     = (const float*)d_in[6];
    const float* b2     = (const float*)d_in[7];
    const float* conv_w = (const float*)d_in[8];
    const float* conv_b = (const float*)d_in[9];
    float* out = (float*)d_out;

    float* f   = (float*)d_ws;                 // H*NN*D  = 69632 floats
    float* hdn = f + H * NN * D;               // H*NN*M  = 34816 floats
    float* att = hdn + H * NN * M;             // H*NN*NN =  2312 floats

    k1_f  <<<H * NN * 4, 128, 0, stream>>>(Xs, FC, f);
    k2_hdn<<<H * NN * 2, 128, 0, stream>>>(f, ROIs, W1, b1, hdn);
    k3_att<<<H,          320, 0, stream>>>(hdn, W2, b2, att);
    k4_out<<<NN * 4,     128, 0, stream>>>(f, att, conv_w, conv_b, Xs, ROIs, out);
}

// Round 4
// 116.915 us; speedup vs baseline: 1.3761x; 1.0346x over previous
//
#include <hip/hip_runtime.h>

#define NN 17    // nodes
#define D  512   // feature dim
#define H  8     // heads
#define C1 515   // D + 3
#define M  256   // hidden

#define XPAD 20                              // [d][n] row stride (17 + pad)
#define RSN  36                              // reduction row: 32 e + pad
#define RSG  (NN * RSN)                      // 612 floats per group
#define SMEM_FL (32 * RSG)                   // 19584 floats = 78.3 KB (union buffer)

__device__ __forceinline__ void fma4(float4& a, float x, const float4& w) {
    a.x = fmaf(x, w.x, a.x); a.y = fmaf(x, w.y, a.y);
    a.z = fmaf(x, w.z, a.z); a.w = fmaf(x, w.w, a.w);
}

// K1: f[h,n,e] = relu(Xs @ FC[h]); FC read exactly once.
// grid = H*16 (e-tiles of 32), block = 256. tw=t&7 -> float4 e; cg=t>>3 (32
// groups) -> d = cg + 32*i (consecutive cg => consecutive d => conflict-free
// LDS broadcast reads). Per-thread: 17 float4 accumulators.
__global__ __launch_bounds__(256) void k1_f(const float* __restrict__ Xs,
                                            const float* __restrict__ FC,
                                            float* __restrict__ f) {
    const int b = blockIdx.x;
    const int et = b & 15, h = b >> 4;
    const int t = threadIdx.x, tw = t & 7, cg = t >> 3;
    __shared__ float sm[SMEM_FL];   // phase 1: xs_t [d][XPAD]; phase 2: red [cg][n][RSN]
    for (int i = t; i < NN * D; i += 256) {
        const int n = i >> 9, d = i & 511;
        sm[d * XPAD + n] = Xs[i];
    }
    __syncthreads();
    float4 acc[NN];
#pragma unroll
    for (int n = 0; n < NN; ++n) acc[n] = make_float4(0.f, 0.f, 0.f, 0.f);
    const float4* fc4 = (const float4*)(FC + (size_t)h * D * D) + et * 8 + tw;
#pragma unroll 4
    for (int i = 0; i < 16; ++i) {
        const int d = cg + (i << 5);
        const float4 w = fc4[d << 7];            // [d][512/4] row stride 128
        const float* xr = sm + d * XPAD;
#pragma unroll
        for (int n4 = 0; n4 < 4; ++n4) {
            const float4 x = *(const float4*)(xr + (n4 << 2));
            fma4(acc[n4 * 4 + 0], x.x, w);
            fma4(acc[n4 * 4 + 1], x.y, w);
            fma4(acc[n4 * 4 + 2], x.z, w);
            fma4(acc[n4 * 4 + 3], x.w, w);
        }
        fma4(acc[16], xr[16], w);
    }
    __syncthreads();                 // all xs_t reads done; reuse smem for reduction
    float* rr = sm + cg * RSG + tw * 4;
#pragma unroll
    for (int n = 0; n < NN; ++n) *(float4*)(rr + n * RSN) = acc[n];
    __syncthreads();
    for (int i = t; i < NN * 32; i += 256) {
        const int n = i >> 5, e = i & 31;
        float s = 0.f;
#pragma unroll 8
        for (int g = 0; g < 32; ++g) s += sm[g * RSG + n * RSN + e];
        f[((h * NN + n) << 9) + (et << 5) + e] = fmaxf(s, 0.f);
    }
}

// K2: hdn[h,n,m] = tanh([f,ROI] @ W1[h] + b1[h]); W1 read exactly once.
// grid = H*8 (m-tiles of 32), block = 256; c = cg + 32*i, tail c=512+cg (cg<3).
__global__ __launch_bounds__(256) void k2_hdn(const float* __restrict__ f,
                                              const float* __restrict__ ROIs,
                                              const float* __restrict__ W1,
                                              const float* __restrict__ b1,
                                              float* __restrict__ hdn) {
    const int b = blockIdx.x;
    const int mt = b & 7, h = b >> 3;
    const int t = threadIdx.x, tw = t & 7, cg = t >> 3;
    __shared__ float sm[SMEM_FL];
    for (int i = t; i < NN * D; i += 256) {
        const int n = i >> 9, d = i & 511;
        sm[d * XPAD + n] = f[((size_t)(h * NN) << 9) + i];
    }
    if (t < NN * 3) {
        const int n = t / 3, cc = t % 3;
        sm[(D + cc) * XPAD + n] = ROIs[t];
    }
    __syncthreads();
    float4 acc[NN];
#pragma unroll
    for (int n = 0; n < NN; ++n) acc[n] = make_float4(0.f, 0.f, 0.f, 0.f);
    const float4* w4 = (const float4*)(W1 + (size_t)h * C1 * M) + mt * 8 + tw;
#pragma unroll 4
    for (int i = 0; i < 16; ++i) {
        const int c = cg + (i << 5);
        const float4 w = w4[c << 6];             // [c][256/4] row stride 64
        const float* xr = sm + c * XPAD;
#pragma unroll
        for (int n4 = 0; n4 < 4; ++n4) {
            const float4 x = *(const float4*)(xr + (n4 << 2));
            fma4(acc[n4 * 4 + 0], x.x, w);
            fma4(acc[n4 * 4 + 1], x.y, w);
            fma4(acc[n4 * 4 + 2], x.z, w);
            fma4(acc[n4 * 4 + 3], x.w, w);
        }
        fma4(acc[16], xr[16], w);
    }
    if (cg < 3) {                                // tail rows c = 512..514 (ROI)
        const int c = D + cg;
        const float4 w = w4[c << 6];
        const float* xr = sm + c * XPAD;
#pragma unroll
        for (int n4 = 0; n4 < 4; ++n4) {
            const float4 x = *(const float4*)(xr + (n4 << 2));
            fma4(acc[n4 * 4 + 0], x.x, w);
            fma4(acc[n4 * 4 + 1], x.y, w);
            fma4(acc[n4 * 4 + 2], x.z, w);
            fma4(acc[n4 * 4 + 3], x.w, w);
        }
        fma4(acc[16], xr[16], w);
    }
    __syncthreads();
    float* rr = sm + cg * RSG + tw * 4;
#pragma unroll
    for (int n = 0; n < NN; ++n) *(float4*)(rr + n * RSN) = acc[n];
    __syncthreads();
    for (int i = t; i < NN * 32; i += 256) {
        const int n = i >> 5, m = i & 31;
        float s = b1[h * M + (mt << 5) + m];
#pragma unroll 8
        for (int g = 0; g < 32; ++g) s += sm[g * RSG + n * RSN + m];
        hdn[(h * NN + n) * M + (mt << 5) + m] = tanhf(s);
    }
}

// K3: scores = hdn[h] @ W2[h] + b2[h]; softmax over n per (h,k) -> att[h,k,n].
// grid = H blocks, block = 320. W2 staged transposed for float4 dots.
__global__ void k3_att(const float* __restrict__ hdn, const float* __restrict__ W2,
                       const float* __restrict__ b2, float* __restrict__ att) {
    const int h = blockIdx.x, t = threadIdx.x;
    __shared__ float sh[NN * M];     // [n][m]
    __shared__ float swt[NN * M];    // [k][m] (transposed W2[h])
    __shared__ float sa[NN * NN];    // scores [k][n]
    for (int i = t; i < NN * M; i += 320) sh[i] = hdn[h * NN * M + i];
    for (int i = t; i < NN * M; i += 320) {
        const int m = i / NN, k = i % NN;
        swt[k * M + m] = W2[(size_t)h * M * NN + i];
    }
    __syncthreads();
    if (t < NN * NN) {
        const int n = t / NN, k = t % NN;
        float acc = b2[h * NN + k];
        const float* a = sh + n * M;
        const float* w = swt + k * M;
#pragma unroll 8
        for (int m = 0; m < M; m += 4) {
            const float4 av = *(const float4*)(a + m);
            const float4 wv = *(const float4*)(w + m);
            acc = fmaf(av.x, wv.x, acc); acc = fmaf(av.y, wv.y, acc);
            acc = fmaf(av.z, wv.z, acc); acc = fmaf(av.w, wv.w, acc);
        }
        sa[k * NN + n] = acc;
    }
    __syncthreads();
    if (t < NN) {
        const int k = t;
        float mx = -1e30f;
        for (int n = 0; n < NN; ++n) mx = fmaxf(mx, sa[k * NN + n]);
        float e[NN];
        float s = 0.f;
        for (int n = 0; n < NN; ++n) { e[n] = __expf(sa[k * NN + n] - mx); s += e[n]; }
        const float inv = 1.f / s;
        for (int n = 0; n < NN; ++n) att[(h * NN + k) * NN + n] = e[n] * inv;
    }
}

// K4: out[k,d] = relu(sum_h cw[h] * sum_n att[h,k,n]*f[h,n,d] + cb) + Xs[k,d]
// grid = NN*4 (d-tiles of 128), block = 128.
__global__ void k4_out(const float* __restrict__ f, const float* __restrict__ att,
                       const float* __restrict__ conv_w, const float* __restrict__ conv_b,
                       const float* __restrict__ Xs, const float* __restrict__ ROIs,
                       float* __restrict__ out) {
    const int b = blockIdx.x;
    const int k = b >> 2, dt = b & 3;
    const int t = threadIdx.x;
    const int d = dt * 128 + t;
    __shared__ float sa[H * NN];
    __shared__ float cw[H];
    for (int i = t; i < H * NN; i += 128) {      // H*NN=136 > 128: strided
        const int h = i / NN, n = i % NN;
        sa[i] = att[(h * NN + k) * NN + n];
    }
    if (t < H) cw[t] = conv_w[t];
    __syncthreads();
    float acc = 0.f;
#pragma unroll
    for (int h = 0; h < H; ++h) {
        float wsum = 0.f;
#pragma unroll
        for (int n = 0; n < NN; ++n)
            wsum = fmaf(sa[h * NN + n], f[(size_t)(h * NN + n) * D + d], wsum);
        acc = fmaf(cw[h], wsum, acc);
    }
    out[k * D + d] = fmaxf(acc + conv_b[0], 0.f) + Xs[k * D + d];
    if (k == 0 && dt == 0 && t < NN * 3) out[NN * D + t] = ROIs[t];
}

extern "C" void kernel_launch(void* const* d_in, const int* in_sizes, int n_in,
                              void* d_out, int out_size, void* d_ws, size_t ws_size,
                              hipStream_t stream) {
    const float* Xs     = (const float*)d_in[0];
    const float* ROIs   = (const float*)d_in[1];
    // d_in[2] = adj, unused
    const float* FC     = (const float*)d_in[3];
    const float* W1     = (const float*)d_in[4];
    const float* b1     = (const float*)d_in[5];
    const float* W2     = (const float*)d_in[6];
    const float* b2     = (const float*)d_in[7];
    const float* conv_w = (const float*)d_in[8];
    const float* conv_b = (const float*)d_in[9];
    float* out = (float*)d_out;

    float* f   = (float*)d_ws;                 // H*NN*D  = 69632 floats
    float* hdn = f + H * NN * D;               // H*NN*M  = 34816 floats
    float* att = hdn + H * NN * M;             // H*NN*NN =  2312 floats

    k1_f  <<<H * 16, 256, 0, stream>>>(Xs, FC, f);
    k2_hdn<<<H * 8,  256, 0, stream>>>(f, ROIs, W1, b1, hdn);
    k3_att<<<H,      320, 0, stream>>>(hdn, W2, b2, att);
    k4_out<<<NN * 4, 128, 0, stream>>>(f, att, conv_w, conv_b, Xs, ROIs, out);
}

// Round 5
// 107.324 us; speedup vs baseline: 1.4990x; 1.0894x over previous
//
#include <hip/hip_runtime.h>

#define NN 17    // nodes
#define D  512   // feature dim
#define H  8     // heads
#define C1 515   // D + 3
#define M  256   // hidden

#define XPAD 20                              // [d][n] row stride (17 + pad)
#define RSN  36                              // reduction row: 32 e + pad
#define RSG  (NN * RSN)                      // 612 floats per group
#define SMEM_FL (32 * RSG)                   // 19584 floats = 78.3 KB (union buffer)

__device__ __forceinline__ void fma4(float4& a, float x, const float4& w) {
    a.x = fmaf(x, w.x, a.x); a.y = fmaf(x, w.y, a.y);
    a.z = fmaf(x, w.z, a.z); a.w = fmaf(x, w.w, a.w);
}

// K1: f[h,n,e] = relu(Xs @ FC[h]); FC read exactly once.
// grid = H*16 (e-tiles of 32), block = 256. tw=t&7 -> float4 e; cg=t>>3 (32
// groups) -> d = cg + 32*i. Per-thread: 17 float4 accumulators.
__global__ __launch_bounds__(256) void k1_f(const float* __restrict__ Xs,
                                            const float* __restrict__ FC,
                                            float* __restrict__ f) {
    const int b = blockIdx.x;
    const int et = b & 15, h = b >> 4;
    const int t = threadIdx.x, tw = t & 7, cg = t >> 3;
    __shared__ float sm[SMEM_FL];   // phase 1: xs_t [d][XPAD]; phase 2: red [cg][n][RSN]
    for (int i = t; i < NN * D; i += 256) {
        const int n = i >> 9, d = i & 511;
        sm[d * XPAD + n] = Xs[i];
    }
    __syncthreads();
    float4 acc[NN];
#pragma unroll
    for (int n = 0; n < NN; ++n) acc[n] = make_float4(0.f, 0.f, 0.f, 0.f);
    const float4* fc4 = (const float4*)(FC + (size_t)h * D * D) + et * 8 + tw;
#pragma unroll 4
    for (int i = 0; i < 16; ++i) {
        const int d = cg + (i << 5);
        const float4 w = fc4[d << 7];            // [d][512/4] row stride 128
        const float* xr = sm + d * XPAD;
#pragma unroll
        for (int n4 = 0; n4 < 4; ++n4) {
            const float4 x = *(const float4*)(xr + (n4 << 2));
            fma4(acc[n4 * 4 + 0], x.x, w);
            fma4(acc[n4 * 4 + 1], x.y, w);
            fma4(acc[n4 * 4 + 2], x.z, w);
            fma4(acc[n4 * 4 + 3], x.w, w);
        }
        fma4(acc[16], xr[16], w);
    }
    __syncthreads();                 // all xs_t reads done; reuse smem for reduction
    float* rr = sm + cg * RSG + tw * 4;
#pragma unroll
    for (int n = 0; n < NN; ++n) *(float4*)(rr + n * RSN) = acc[n];
    __syncthreads();
    for (int i = t; i < NN * 32; i += 256) {
        const int n = i >> 5, e = i & 31;
        float s = 0.f;
#pragma unroll 8
        for (int g = 0; g < 32; ++g) s += sm[g * RSG + n * RSN + e];
        f[((h * NN + n) << 9) + (et << 5) + e] = fmaxf(s, 0.f);
    }
}

// K2: hdn[h,n,m] = tanh([f,ROI] @ W1[h] + b1[h]); W1 read exactly once.
// grid = H*8 (m-tiles of 32), block = 256; c = cg + 32*i, tail c=512+cg (cg<3).
__global__ __launch_bounds__(256) void k2_hdn(const float* __restrict__ f,
                                              const float* __restrict__ ROIs,
                                              const float* __restrict__ W1,
                                              const float* __restrict__ b1,
                                              float* __restrict__ hdn) {
    const int b = blockIdx.x;
    const int mt = b & 7, h = b >> 3;
    const int t = threadIdx.x, tw = t & 7, cg = t >> 3;
    __shared__ float sm[SMEM_FL];
    for (int i = t; i < NN * D; i += 256) {
        const int n = i >> 9, d = i & 511;
        sm[d * XPAD + n] = f[((size_t)(h * NN) << 9) + i];
    }
    if (t < NN * 3) {
        const int n = t / 3, cc = t % 3;
        sm[(D + cc) * XPAD + n] = ROIs[t];
    }
    __syncthreads();
    float4 acc[NN];
#pragma unroll
    for (int n = 0; n < NN; ++n) acc[n] = make_float4(0.f, 0.f, 0.f, 0.f);
    const float4* w4 = (const float4*)(W1 + (size_t)h * C1 * M) + mt * 8 + tw;
#pragma unroll 4
    for (int i = 0; i < 16; ++i) {
        const int c = cg + (i << 5);
        const float4 w = w4[c << 6];             // [c][256/4] row stride 64
        const float* xr = sm + c * XPAD;
#pragma unroll
        for (int n4 = 0; n4 < 4; ++n4) {
            const float4 x = *(const float4*)(xr + (n4 << 2));
            fma4(acc[n4 * 4 + 0], x.x, w);
            fma4(acc[n4 * 4 + 1], x.y, w);
            fma4(acc[n4 * 4 + 2], x.z, w);
            fma4(acc[n4 * 4 + 3], x.w, w);
        }
        fma4(acc[16], xr[16], w);
    }
    if (cg < 3) {                                // tail rows c = 512..514 (ROI)
        const int c = D + cg;
        const float4 w = w4[c << 6];
        const float* xr = sm + c * XPAD;
#pragma unroll
        for (int n4 = 0; n4 < 4; ++n4) {
            const float4 x = *(const float4*)(xr + (n4 << 2));
            fma4(acc[n4 * 4 + 0], x.x, w);
            fma4(acc[n4 * 4 + 1], x.y, w);
            fma4(acc[n4 * 4 + 2], x.z, w);
            fma4(acc[n4 * 4 + 3], x.w, w);
        }
        fma4(acc[16], xr[16], w);
    }
    __syncthreads();
    float* rr = sm + cg * RSG + tw * 4;
#pragma unroll
    for (int n = 0; n < NN; ++n) *(float4*)(rr + n * RSN) = acc[n];
    __syncthreads();
    for (int i = t; i < NN * 32; i += 256) {
        const int n = i >> 5, m = i & 31;
        float s = b1[h * M + (mt << 5) + m];
#pragma unroll 8
        for (int g = 0; g < 32; ++g) s += sm[g * RSG + n * RSN + m];
        hdn[(h * NN + n) * M + (mt << 5) + m] = tanhf(s);
    }
}

// K34 (fused k3+k4): one block per landmark k.
// Phase 1: scores[h,n] = hdn[h,n,:].W2[h,:,k] + b2[h,k] (W2 col staged in LDS)
// Phase 2: softmax over n per h  ->  att weights in LDS
// Phase 3: out[k,d] = relu(sum_h cw[h]*sum_n att[h,n]*f[h,n,d] + cb) + Xs[k,d]
// grid = NN blocks, block = 256 (each thread covers d = t and t+256).
__global__ __launch_bounds__(256) void k34(const float* __restrict__ hdn,
                                           const float* __restrict__ W2,
                                           const float* __restrict__ b2,
                                           const float* __restrict__ f,
                                           const float* __restrict__ conv_w,
                                           const float* __restrict__ conv_b,
                                           const float* __restrict__ Xs,
                                           const float* __restrict__ ROIs,
                                           float* __restrict__ out) {
    const int k = blockIdx.x, t = threadIdx.x;
    __shared__ float swk[H][M + 4];   // W2[h,:,k], row stride 260 (1040 B, 16B-aligned)
    __shared__ float sa[H][NN];       // scores -> att weights
    __shared__ float cw[H];
    // stage W2 column k: i = h*256+m
    for (int i = t; i < H * M; i += 256) {
        const int h = i >> 8, m = i & 255;
        swk[h][m] = W2[(size_t)(h * M + m) * NN + k];
    }
    if (t < H) cw[t] = conv_w[t];
    __syncthreads();
    if (t < H * NN) {
        const int h = t / NN, n = t % NN;
        const float4* a4 = (const float4*)(hdn + (h * NN + n) * M);
        const float4* w4 = (const float4*)(&swk[h][0]);
        float acc = b2[h * NN + k];
#pragma unroll 8
        for (int m4 = 0; m4 < M / 4; ++m4) {
            const float4 av = a4[m4];
            const float4 wv = w4[m4];
            acc = fmaf(av.x, wv.x, acc); acc = fmaf(av.y, wv.y, acc);
            acc = fmaf(av.z, wv.z, acc); acc = fmaf(av.w, wv.w, acc);
        }
        sa[h][n] = acc;
    }
    __syncthreads();
    if (t < H) {
        float mx = -1e30f;
#pragma unroll
        for (int n = 0; n < NN; ++n) mx = fmaxf(mx, sa[t][n]);
        float e[NN];
        float s = 0.f;
#pragma unroll
        for (int n = 0; n < NN; ++n) { e[n] = __expf(sa[t][n] - mx); s += e[n]; }
        const float inv = 1.f / s;
#pragma unroll
        for (int n = 0; n < NN; ++n) sa[t][n] = e[n] * inv;
    }
    __syncthreads();
    const float cb = conv_b[0];
    float acc0 = 0.f, acc1 = 0.f;
    for (int h = 0; h < H; ++h) {
        float w0 = 0.f, w1 = 0.f;
#pragma unroll
        for (int n = 0; n < NN; ++n) {
            const float a = sa[h][n];
            const float* fr = f + (size_t)((h * NN + n) << 9);
            w0 = fmaf(a, fr[t], w0);
            w1 = fmaf(a, fr[t + 256], w1);
        }
        acc0 = fmaf(cw[h], w0, acc0);
        acc1 = fmaf(cw[h], w1, acc1);
    }
    out[(k << 9) + t]       = fmaxf(acc0 + cb, 0.f) + Xs[(k << 9) + t];
    out[(k << 9) + t + 256] = fmaxf(acc1 + cb, 0.f) + Xs[(k << 9) + t + 256];
    if (k == 0 && t < NN * 3) out[NN * D + t] = ROIs[t];
}

extern "C" void kernel_launch(void* const* d_in, const int* in_sizes, int n_in,
                              void* d_out, int out_size, void* d_ws, size_t ws_size,
                              hipStream_t stream) {
    const float* Xs     = (const float*)d_in[0];
    const float* ROIs   = (const float*)d_in[1];
    // d_in[2] = adj, unused
    const float* FC     = (const float*)d_in[3];
    const float* W1     = (const float*)d_in[4];
    const float* b1     = (const float*)d_in[5];
    const float* W2     = (const float*)d_in[6];
    const float* b2     = (const float*)d_in[7];
    const float* conv_w = (const float*)d_in[8];
    const float* conv_b = (const float*)d_in[9];
    float* out = (float*)d_out;

    float* f   = (float*)d_ws;                 // H*NN*D  = 69632 floats
    float* hdn = f + H * NN * D;               // H*NN*M  = 34816 floats

    k1_f  <<<H * 16, 256, 0, stream>>>(Xs, FC, f);
    k2_hdn<<<H * 8,  256, 0, stream>>>(f, ROIs, W1, b1, hdn);
    k34   <<<NN,     256, 0, stream>>>(hdn, W2, b2, f, conv_w, conv_b, Xs, ROIs, out);
}